// Round 1
// baseline (365.605 us; speedup 1.0000x reference)
//
#include <hip/hip_runtime.h>
#include <hip/hip_bf16.h>

// ---------------- helpers ----------------
typedef __attribute__((ext_vector_type(8))) short bf16x8;
typedef __attribute__((ext_vector_type(4))) float f32x4;
typedef __attribute__((ext_vector_type(2))) float f32x2;

__device__ __forceinline__ unsigned short f2bf(float f) {
    __hip_bfloat16 h = __float2bfloat16(f);   // round-to-nearest-even
    return __builtin_bit_cast(unsigned short, h);
}
// unpack packed bf16 pair -> f32x2 {lo, hi}
__device__ __forceinline__ f32x2 up2(unsigned int u) {
    f32x2 r;
    r.x = __builtin_bit_cast(float, u << 16);
    r.y = __builtin_bit_cast(float, u & 0xffff0000u);
    return r;
}
__device__ __forceinline__ unsigned int packbf(float lo, float hi) {
    return (unsigned int)f2bf(lo) | ((unsigned int)f2bf(hi) << 16);
}

// ---------------- CSR build ----------------
// Harness delivers integer inputs as int32. k_hist captures each edge's
// intra-bucket rank (atomicAdd old value) so the fill pass needs no atomics.
__global__ void k_hist(const int* __restrict__ dst, int* __restrict__ counts,
                       int* __restrict__ rank, int E) {
    int e = blockIdx.x * blockDim.x + threadIdx.x;
    if (e < E) rank[e] = atomicAdd(&counts[dst[e]], 1);
}

__global__ void k_psum(const int* __restrict__ counts, int* __restrict__ part, int NN) {
    __shared__ int s[256];
    int t = threadIdx.x;
    int i = blockIdx.x * 256 + t;
    s[t] = (i < NN) ? counts[i] : 0;
    __syncthreads();
    for (int off = 128; off > 0; off >>= 1) {
        if (t < off) s[t] += s[t + off];
        __syncthreads();
    }
    if (t == 0) part[blockIdx.x] = s[0];
}

// local scan + inline reduction of preceding block partials (nb <= 256)
__global__ void k_scatter_rs(const int* __restrict__ counts, const int* __restrict__ part,
                             int* __restrict__ row_start, int NN, int E) {
    __shared__ int s[256];
    __shared__ int q[256];
    int t = threadIdx.x;
    int b = blockIdx.x;
    q[t] = (t < b) ? part[t] : 0;
    __syncthreads();
    for (int off = 128; off > 0; off >>= 1) {
        if (t < off) q[t] += q[t + off];
        __syncthreads();
    }
    int boff = q[0];
    __syncthreads();
    int i = b * 256 + t;
    int v = (i < NN) ? counts[i] : 0;
    s[t] = v; __syncthreads();
    for (int off = 1; off < 256; off <<= 1) {
        int u = (t >= off) ? s[t - off] : 0;
        __syncthreads();
        s[t] += u;
        __syncthreads();
    }
    int ex = s[t] - v + boff;
    if (i < NN) row_start[i] = ex;
    if (i == NN - 1) row_start[NN] = E;
}

// atomic-free fill; node ids < 65536 so csrc is ushort (halves index traffic)
__global__ void k_fill(const int* __restrict__ src, const int* __restrict__ dst,
                       const int* __restrict__ rank, const int* __restrict__ row_start,
                       unsigned short* __restrict__ csrc, int E) {
    int e = blockIdx.x * blockDim.x + threadIdx.x;
    if (e < E) csrc[row_start[dst[e]] + rank[e]] = (unsigned short)src[e];
}

// ---------------- fused dtype conversions (one launch) ----------------
__global__ void k_cvt_all(const float4* __restrict__ x4, ushort4* __restrict__ xb4, int n4x, int nbx,
                          const float* __restrict__ W1, unsigned short* __restrict__ w1t,
                          const float* __restrict__ W2, unsigned short* __restrict__ w2t,
                          const float* __restrict__ W3, unsigned short* __restrict__ w3t) {
    int b = blockIdx.x;
    if (b < nbx) {
        int i = b * 256 + threadIdx.x;
        if (i < n4x) {
            float4 v = x4[i];
            ushort4 o; o.x = f2bf(v.x); o.y = f2bf(v.y); o.z = f2bf(v.z); o.w = f2bf(v.w);
            xb4[i] = o;
        }
        return;
    }
    b -= nbx;
    const float* w; unsigned short* wt; int K;
    if (b < 128)      { w = W1; wt = w1t; K = 128; }
    else if (b < 384) { w = W2; wt = w2t; K = 256; b -= 128; }
    else              { w = W3; wt = w3t; K = 256; b -= 384; }
    int i = b * 256 + threadIdx.x;   // i < K*256
    int k = i >> 8, n = i & 255;
    wt[n * K + k] = f2bf(w[i]);
}

// ---------------- bf16 CSR aggregation (layer 1, x table) ----------------
template <int F>   // F=128 here: 8 B/lane rows
__global__ __launch_bounds__(256)
void k_agg(const unsigned short* __restrict__ h, const int* __restrict__ rs,
           const unsigned short* __restrict__ csrc, unsigned short* __restrict__ out, int NN) {
    int gid = blockIdx.x * blockDim.x + threadIdx.x;
    int node = gid >> 6;
    if (node >= NN) return;
    int lane = threadIdx.x & 63;
    int half = lane >> 5, l32 = lane & 31;
    int k0 = rs[node], k1 = rs[node + 1];
    int cnt = k1 - k0;

    constexpr int NP = (F == 256) ? 4 : 2;
    f32x2 acc[4][NP];
#pragma unroll
    for (int b = 0; b < 4; ++b)
#pragma unroll
        for (int i = 0; i < NP; ++i) acc[b][i] = (f32x2){0.f, 0.f};

    for (int base = 0; base < cnt; base += 64) {
        int nk = min(cnt - base, 64);
        int myidx = (lane < nk) ? (int)csrc[k0 + base + lane] : 0;
        int j = 0;
        for (; j + 8 <= nk; j += 8) {
            int s[4];
#pragma unroll
            for (int b = 0; b < 4; ++b) s[b] = __shfl(myidx, j + 2 * b + half, 64);
#pragma unroll
            for (int b = 0; b < 4; ++b) {
                if constexpr (F == 256) {
                    uint4 v = ((const uint4*)(h + (size_t)s[b] * F))[l32];
                    acc[b][0] += up2(v.x); acc[b][1] += up2(v.y);
                    acc[b][2] += up2(v.z); acc[b][3] += up2(v.w);
                } else {
                    uint2 v = ((const uint2*)(h + (size_t)s[b] * F))[l32];
                    acc[b][0] += up2(v.x); acc[b][1] += up2(v.y);
                }
            }
        }
        for (; j < nk; j += 2) {
            int jj = j + half;
            int s = __shfl(myidx, jj < nk ? jj : 0, 64);
            if (jj < nk) {
                if constexpr (F == 256) {
                    uint4 v = ((const uint4*)(h + (size_t)s * F))[l32];
                    acc[0][0] += up2(v.x); acc[0][1] += up2(v.y);
                    acc[0][2] += up2(v.z); acc[0][3] += up2(v.w);
                } else {
                    uint2 v = ((const uint2*)(h + (size_t)s * F))[l32];
                    acc[0][0] += up2(v.x); acc[0][1] += up2(v.y);
                }
            }
        }
    }

#pragma unroll
    for (int i = 0; i < NP; ++i) {
        acc[0][i] += acc[1][i];
        acc[2][i] += acc[3][i];
        acc[0][i] += acc[2][i];
    }
#pragma unroll
    for (int i = 0; i < NP; ++i) {
        acc[0][i].x += __shfl(acc[0][i].x, l32 + 32, 64);
        acc[0][i].y += __shfl(acc[0][i].y, l32 + 32, 64);
    }
    if (half == 0) {
        if constexpr (F == 256) {
            uint4 o;
            o.x = packbf(acc[0][0].x, acc[0][0].y); o.y = packbf(acc[0][1].x, acc[0][1].y);
            o.z = packbf(acc[0][2].x, acc[0][2].y); o.w = packbf(acc[0][3].x, acc[0][3].y);
            ((uint4*)(out + (size_t)node * F))[l32] = o;
        } else {
            uint2 o;
            o.x = packbf(acc[0][0].x, acc[0][0].y); o.y = packbf(acc[0][1].x, acc[0][1].y);
            ((uint2*)(out + (size_t)node * F))[l32] = o;
        }
    }
}

// ---------------- int8 CSR aggregation (layers 2&3) ----------------
// h rows are uint8 (256 B = 2 cache lines vs 4 for bf16) with per-(node,
// 64-col) fp32 scales. Agg was line-rate-limited (rounds 4-7: 174 MB @ 25
// G lines/s regardless of MLP depth) -> halving lines halves time.
__global__ __launch_bounds__(256)
void k_agg8(const unsigned char* __restrict__ h8, const float* __restrict__ scales,
            const int* __restrict__ rs, const unsigned short* __restrict__ csrc,
            unsigned short* __restrict__ out, int NN) {
    int gid = blockIdx.x * blockDim.x + threadIdx.x;
    int node = gid >> 6;
    if (node >= NN) return;
    int lane = threadIdx.x & 63;
    int half = lane >> 5, l32 = lane & 31;
    int qoff = l32 >> 3;               // 64-col quarter of this lane's 8 feats
    int k0 = rs[node], k1 = rs[node + 1];
    int cnt = k1 - k0;

    f32x2 acc[4][4];
#pragma unroll
    for (int b = 0; b < 4; ++b)
#pragma unroll
        for (int i = 0; i < 4; ++i) acc[b][i] = (f32x2){0.f, 0.f};

    auto accum = [&](int b, uint2 v, float sc) {
        unsigned x = v.x, y = v.y;
        acc[b][0].x += (float)(x & 0xff) * sc;
        acc[b][0].y += (float)((x >> 8) & 0xff) * sc;
        acc[b][1].x += (float)((x >> 16) & 0xff) * sc;
        acc[b][1].y += (float)(x >> 24) * sc;
        acc[b][2].x += (float)(y & 0xff) * sc;
        acc[b][2].y += (float)((y >> 8) & 0xff) * sc;
        acc[b][3].x += (float)((y >> 16) & 0xff) * sc;
        acc[b][3].y += (float)(y >> 24) * sc;
    };

    for (int base = 0; base < cnt; base += 64) {
        int nk = min(cnt - base, 64);
        int myidx = (lane < nk) ? (int)csrc[k0 + base + lane] : 0;
        int j = 0;
        for (; j + 8 <= nk; j += 8) {
            int s[4]; uint2 v[4]; float sc[4];
#pragma unroll
            for (int b = 0; b < 4; ++b) s[b] = __shfl(myidx, j + 2 * b + half, 64);
#pragma unroll
            for (int b = 0; b < 4; ++b) {
                v[b] = ((const uint2*)(h8 + (size_t)s[b] * 256))[l32];
                sc[b] = scales[s[b] * 4 + qoff];
            }
#pragma unroll
            for (int b = 0; b < 4; ++b) accum(b, v[b], sc[b]);
        }
        for (; j < nk; j += 2) {
            int jj = j + half;
            int s = __shfl(myidx, jj < nk ? jj : 0, 64);
            if (jj < nk) {
                uint2 v = ((const uint2*)(h8 + (size_t)s * 256))[l32];
                float sc = scales[s * 4 + qoff];
                accum(0, v, sc);
            }
        }
    }

#pragma unroll
    for (int i = 0; i < 4; ++i) {
        acc[0][i] += acc[1][i];
        acc[2][i] += acc[3][i];
        acc[0][i] += acc[2][i];
    }
#pragma unroll
    for (int i = 0; i < 4; ++i) {
        acc[0][i].x += __shfl(acc[0][i].x, l32 + 32, 64);
        acc[0][i].y += __shfl(acc[0][i].y, l32 + 32, 64);
    }
    if (half == 0) {
        uint4 o;
        o.x = packbf(acc[0][0].x, acc[0][0].y); o.y = packbf(acc[0][1].x, acc[0][1].y);
        o.z = packbf(acc[0][2].x, acc[0][2].y); o.w = packbf(acc[0][3].x, acc[0][3].y);
        ((uint4*)(out + (size_t)node * 256))[l32] = o;
    }
}

// ---------------- MFMA GEMM: C = relu(A @ W + b) ----------------
// Barrier-free, LDS-free rewrite. Old LDS-staged 2-barrier K-loop was
// latency-bound (MfmaUtil 4.2%, HBM 18%, occ 20%): every K-step made all
// waves ride a full global->VGPR->LDS->barrier round-trip with only ~12
// waves/CU to hide it. K is tiny (<=256) and B (weights) is 128 KB and
// L2-resident, so staging buys nothing: direct A-fragment loads are
// perfectly line-efficient (lanes l16 cover 16 rows, quads 0-3 cover the
// full 64 B of each row), and intra-block duplicate A reads hit L1/L2.
// Block = 4 waves; wave w computes rows mbase..mbase+63 x cols w*64..+63.
// K templated -> full unroll, compiler pipelines independent 16 B loads.
// QUANT=true: write uint8 h + per-(row, 64-col) fp32 scale (in-wave rowmax
// via shfl_xor over the 16-lane quad). QUANT=false: fp32 out (final layer).
template <bool QUANT, int K>
__global__ __launch_bounds__(256, 3)
void k_gemm(const unsigned short* __restrict__ A, const unsigned short* __restrict__ Bt,
            const float* __restrict__ bias, void* __restrict__ Cout,
            float* __restrict__ scales, int M) {
    int tid = threadIdx.x;
    int mbase = blockIdx.x * 64;
    int lane = tid & 63, quad = lane >> 4, l16 = lane & 15;
    int wn = tid >> 6;                 // wave's 64-col slab (N=256 fixed)

    // fragment base pointers (A rows clamped; tail rows never stored)
    const unsigned short* Ap[4];
#pragma unroll
    for (int mt = 0; mt < 4; ++mt) {
        int r = mbase + mt * 16 + l16;
        if (r >= M) r = M - 1;
        Ap[mt] = A + (size_t)r * K + quad * 8;
    }
    const unsigned short* Bp[4];
#pragma unroll
    for (int nt = 0; nt < 4; ++nt)
        Bp[nt] = Bt + (size_t)(wn * 64 + nt * 16 + l16) * K + quad * 8;

    f32x4 acc[4][4];
#pragma unroll
    for (int i = 0; i < 4; ++i)
#pragma unroll
        for (int j = 0; j < 4; ++j) acc[i][j] = (f32x4){0.f, 0.f, 0.f, 0.f};

#pragma unroll
    for (int kk = 0; kk < K; kk += 32) {
        bf16x8 af[4], bfr[4];
#pragma unroll
        for (int mt = 0; mt < 4; ++mt) af[mt] = *((const bf16x8*)(Ap[mt] + kk));
#pragma unroll
        for (int nt = 0; nt < 4; ++nt) bfr[nt] = *((const bf16x8*)(Bp[nt] + kk));
#pragma unroll
        for (int mt = 0; mt < 4; ++mt)
#pragma unroll
            for (int nt = 0; nt < 4; ++nt)
                acc[mt][nt] = __builtin_amdgcn_mfma_f32_16x16x32_bf16(af[mt], bfr[nt], acc[mt][nt], 0, 0, 0);
    }

    // bias + relu in-place.  C/D layout: col = lane&15, row = quad*4 + reg
    float bv[4];
#pragma unroll
    for (int nt = 0; nt < 4; ++nt) bv[nt] = bias[wn * 64 + nt * 16 + l16];
#pragma unroll
    for (int mt = 0; mt < 4; ++mt)
#pragma unroll
        for (int nt = 0; nt < 4; ++nt)
#pragma unroll
            for (int r = 0; r < 4; ++r) {
                float v = acc[mt][nt][r] + bv[nt];
                acc[mt][nt][r] = v > 0.f ? v : 0.f;
            }

    if constexpr (QUANT) {
        unsigned char* h8 = (unsigned char*)Cout;
        int qid = wn;                  // 64-col quarter id
#pragma unroll
        for (int mt = 0; mt < 4; ++mt) {
#pragma unroll
            for (int r = 0; r < 4; ++r) {
                float mx = fmaxf(fmaxf(acc[mt][0][r], acc[mt][1][r]),
                                 fmaxf(acc[mt][2][r], acc[mt][3][r]));
#pragma unroll
                for (int off = 1; off < 16; off <<= 1)
                    mx = fmaxf(mx, __shfl_xor(mx, off, 64));
                float inv = mx > 0.f ? 255.0f / mx : 0.0f;
                int m = mbase + mt * 16 + quad * 4 + r;
                if (m < M) {
#pragma unroll
                    for (int nt = 0; nt < 4; ++nt) {
                        int n = wn * 64 + nt * 16 + l16;
                        unsigned u = (unsigned)(acc[mt][nt][r] * inv + 0.5f);
                        h8[(size_t)m * 256 + n] = (unsigned char)u;
                    }
                    if (l16 == 0) scales[(size_t)m * 4 + qid] = mx * (1.0f / 255.0f);
                }
            }
        }
    } else {
        float* C = (float*)Cout;
#pragma unroll
        for (int mt = 0; mt < 4; ++mt)
#pragma unroll
            for (int nt = 0; nt < 4; ++nt) {
                int n = wn * 64 + nt * 16 + l16;
#pragma unroll
                for (int r = 0; r < 4; ++r) {
                    int m = mbase + mt * 16 + quad * 4 + r;
                    if (m < M) C[(size_t)m * 256 + n] = acc[mt][nt][r];
                }
            }
    }
}

// ---------------- host ----------------
static inline size_t alignup(size_t x) { return (x + 255) & ~(size_t)255; }

extern "C" void kernel_launch(void* const* d_in, const int* in_sizes, int n_in,
                              void* d_out, int out_size, void* d_ws, size_t ws_size,
                              hipStream_t stream) {
    const float* x  = (const float*)d_in[0];
    const int* ei   = (const int*)d_in[1];    // int32 on device (harness converts)
    const float* W1 = (const float*)d_in[2];
    const float* b1 = (const float*)d_in[3];
    const float* W2 = (const float*)d_in[4];
    const float* b2 = (const float*)d_in[5];
    const float* W3 = (const float*)d_in[6];
    const float* b3 = (const float*)d_in[7];

    const int M = in_sizes[0] / 128;      // 50000 nodes
    const int E = in_sizes[1] / 2;        // 800000 edges
    const int* srcp = ei;
    const int* dstp = ei + E;
    const int nscan = (M + 255) / 256;

    // workspace carve-up (~45 MB). h8 (12.8 MB) + scales (0.8 MB) live in
    // d_out: both dead before gemm3 overwrites d_out with fp32.
    char* p = (char*)d_ws;
    size_t off = 0;
    auto carve = [&](size_t bytes) { void* r = p + off; off += alignup(bytes); return r; };
    int* counts    = (int*)carve((size_t)M * 4);
    int* row_start = (int*)carve((size_t)(M + 1) * 4);
    int* part      = (int*)carve((size_t)256 * 4);
    int* rank      = (int*)carve((size_t)E * 4);
    unsigned short* csrc = (unsigned short*)carve((size_t)E * 2);
    unsigned short* w1t = (unsigned short*)carve((size_t)128 * 256 * 2);
    unsigned short* w2t = (unsigned short*)carve((size_t)256 * 256 * 2);
    unsigned short* w3t = (unsigned short*)carve((size_t)256 * 256 * 2);
    unsigned short* xb  = (unsigned short*)carve((size_t)M * 128 * 2);
    unsigned short* ab  = (unsigned short*)carve((size_t)M * 256 * 2);  // a1/a2/a3 (bf16)
    unsigned char* h8   = (unsigned char*)d_out;                         // h1/h2 int8
    float* scales       = (float*)((char*)d_out + (size_t)M * 256);      // 4 per node

    // 1) CSR build (rank trick: no atomics in fill)
    hipMemsetAsync(counts, 0, (size_t)M * 4, stream);
    k_hist<<<(E + 255) / 256, 256, 0, stream>>>(dstp, counts, rank, E);
    k_psum<<<nscan, 256, 0, stream>>>(counts, part, M);
    k_scatter_rs<<<nscan, 256, 0, stream>>>(counts, part, row_start, M, E);
    k_fill<<<(E + 255) / 256, 256, 0, stream>>>(srcp, dstp, rank, row_start, csrc, E);

    // 2) conversions (single launch)
    int n4x = M * 128 / 4;
    int nbx = (n4x + 255) / 256;
    k_cvt_all<<<nbx + 128 + 256 + 256, 256, 0, stream>>>(
        (const float4*)x, (ushort4*)xb, n4x, nbx, W1, w1t, W2, w2t, W3, w3t);

    dim3 ggrid((M + 63) / 64);
    int aggblocks = (M * 64 + 255) / 256;

    // layer 1: a1 = agg(x); h1 = quant8(relu(a1 @ W1 + b1))
    k_agg<128><<<aggblocks, 256, 0, stream>>>(xb, row_start, csrc, ab, M);
    k_gemm<true, 128><<<ggrid, 256, 0, stream>>>(ab, w1t, b1, h8, scales, M);

    // layer 2: a2 = agg8(h1); h2 = quant8(relu(a2 @ W2 + b2))
    k_agg8<<<aggblocks, 256, 0, stream>>>(h8, scales, row_start, csrc, ab, M);
    k_gemm<true, 256><<<ggrid, 256, 0, stream>>>(ab, w2t, b2, h8, scales, M);

    // layer 3: a3 = agg8(h2); out = relu(a3 @ W3 + b3)
    k_agg8<<<aggblocks, 256, 0, stream>>>(h8, scales, row_start, csrc, ab, M);
    k_gemm<false, 256><<<ggrid, 256, 0, stream>>>(ab, w3t, b3, d_out, nullptr, M);
}